// Round 4
// baseline (813.534 us; speedup 1.0000x reference)
//
#include <hip/hip_runtime.h>

#define N_GRID 128
#define N_GRID3 (N_GRID * N_GRID * N_GRID)

constexpr int   N_PART   = 500000;
constexpr float DT       = 0.0002f;
constexpr float DX       = 1.0f / 128.0f;
constexpr float INV_DX   = 128.0f;
constexpr float P_MASS   = 5.9604644775390625e-05f;   // (DX*0.5)^3 * 1000
constexpr float AFF_COEF = -7.8125e-07f;              // -DT * P_VOL * 4 * INV_DX^2
constexpr float GRAVITY  = 9.8f;
constexpr int   BOUND    = 3;
constexpr float C_SCALE  = 65536.0f;                  // 4 * INV_DX^2

constexpr int NFB  = 32;                  // fine sort blocks per axis (4 cells each)
constexpr int NFB3 = NFB * NFB * NFB;     // 32768 bins
constexpr int NOB  = 16;                  // owner blocks per axis (8 cells each)
constexpr int NOB3 = NOB * NOB * NOB;     // 4096 workgroups

__device__ __forceinline__ void atomAddF(float* p, float v) {
  unsafeAtomicAdd(p, v);  // native ds_add_f32 on LDS
}

// ---------------- pass 1: per-particle fine-block id + histogram ----------------
__global__ __launch_bounds__(256) void k_count(const float* __restrict__ x,
                                               int* __restrict__ bid,
                                               int* __restrict__ cnt) {
  int n = blockIdx.x * 256 + threadIdx.x;
  if (n >= N_PART) return;
  int bx = (int)floorf(x[n * 3 + 0] * INV_DX - 0.5f) >> 2;
  int by = (int)floorf(x[n * 3 + 1] * INV_DX - 0.5f) >> 2;
  int bz = (int)floorf(x[n * 3 + 2] * INV_DX - 0.5f) >> 2;
  bx = min(max(bx, 0), NFB - 1);
  by = min(max(by, 0), NFB - 1);
  bz = min(max(bz, 0), NFB - 1);
  int b = (bx * NFB + by) * NFB + bz;
  bid[n] = b;
  atomicAdd(&cnt[b], 1);
}

// ---------------- pass 2: exclusive scan of 32768 bins (1 workgroup) ----------------
__global__ __launch_bounds__(256) void k_scan(const int* __restrict__ cnt,
                                              int* __restrict__ start,
                                              int* __restrict__ cursor) {
  __shared__ int wsum[4];
  int tid = threadIdx.x;
  int lane = tid & 63, wid = tid >> 6;
  int base = tid * 128;  // 256 threads x 128 bins = 32768
  int tot = 0;
  for (int i = 0; i < 128; ++i) tot += cnt[base + i];
  int incl = tot;
  for (int d = 1; d < 64; d <<= 1) {
    int t = __shfl_up(incl, d);
    if (lane >= d) incl += t;
  }
  if (lane == 63) wsum[wid] = incl;
  __syncthreads();
  int woff = 0;
  for (int w = 0; w < wid; ++w) woff += wsum[w];
  int run = woff + incl - tot;  // exclusive prefix of this thread's chunk
  for (int i = 0; i < 128; ++i) {
    start[base + i] = run;
    cursor[base + i] = run;
    run += cnt[base + i];
  }
  if (tid == 255) start[NFB3] = run;  // == N_PART
}

// ---------------- pass 3: reorder + precompute 64B particle payload ----------------
// payload[pos] = { (px,py,pz,mvx), (mvy,mvz,aff0,aff1), (aff2..5), (aff6..8,pad) }
__global__ __launch_bounds__(256) void k_reorder(
    const float* __restrict__ x, const float* __restrict__ v,
    const float* __restrict__ C, const float* __restrict__ S,
    const int* __restrict__ bid, int* __restrict__ cursor,
    float4* __restrict__ pay) {
  int n = blockIdx.x * 256 + threadIdx.x;
  if (n >= N_PART) return;
  int pos = atomicAdd(&cursor[bid[n]], 1);

  float px = x[n * 3 + 0], py = x[n * 3 + 1], pz = x[n * 3 + 2];
  float mvx = P_MASS * v[n * 3 + 0];
  float mvy = P_MASS * v[n * 3 + 1];
  float mvz = P_MASS * v[n * 3 + 2];
  float aff[9];
#pragma unroll
  for (int k = 0; k < 9; ++k)
    aff[k] = AFF_COEF * S[n * 9 + k] + P_MASS * C[n * 9 + k];

  float4* dst = pay + (size_t)pos * 4;
  dst[0] = make_float4(px, py, pz, mvx);
  dst[1] = make_float4(mvy, mvz, aff[0], aff[1]);
  dst[2] = make_float4(aff[2], aff[3], aff[4], aff[5]);
  dst[3] = make_float4(aff[6], aff[7], aff[8], 0.0f);
}

// ---------------- P2G gather: each WG owns an 8^3 region exclusively ----------------
// Gathers all particles whose stencil touches its cells (9 contiguous sorted
// ranges), accumulates in LDS, then normalizes + gravity + boundary and writes
// FINAL grid velocities with plain stores. Zero global atomics.
__global__ __launch_bounds__(256) void mpm_p2g(
    const int* __restrict__ cellStart, const float4* __restrict__ pay,
    float* __restrict__ grid /* [N_GRID3][4] final velocities */) {
  __shared__ float tile[4][512];

  int b = blockIdx.x;
  int obz = b & (NOB - 1), oby = (b >> 4) & (NOB - 1), obx = b >> 8;
  int ox = obx * 8, oy = oby * 8, oz = obz * 8;

  int fzl = max(2 * obz - 1, 0);
  int fzh1 = 2 * obz + 2;  // exclusive fine-bin end (prefix array is global-monotone)

  // early-out: any particles in the 27-fine-block gather region?
  int total = 0;
  for (int dfx = -1; dfx <= 1; ++dfx) {
    int fx = 2 * obx + dfx;
    if (fx < 0) continue;
    for (int dfy = -1; dfy <= 1; ++dfy) {
      int fy = 2 * oby + dfy;
      if (fy < 0) continue;
      int rowb = (fx * NFB + fy) * NFB;
      total += cellStart[rowb + fzh1] - cellStart[rowb + fzl];
    }
  }
  if (total == 0) return;  // uniform across block; cells never read by g2p

  for (int i = threadIdx.x; i < 512; i += 256) {
    tile[0][i] = 0.0f; tile[1][i] = 0.0f; tile[2][i] = 0.0f; tile[3][i] = 0.0f;
  }
  __syncthreads();

  for (int dfx = -1; dfx <= 1; ++dfx) {
    int fx = 2 * obx + dfx;
    if (fx < 0) continue;
    for (int dfy = -1; dfy <= 1; ++dfy) {
      int fy = 2 * oby + dfy;
      if (fy < 0) continue;
      int rowb = (fx * NFB + fy) * NFB;
      int s = cellStart[rowb + fzl];
      int e = cellStart[rowb + fzh1];
      for (int i = s + (int)threadIdx.x; i < e; i += 256) {
        const float4* src = pay + (size_t)i * 4;
        float4 q0 = src[0], q1 = src[1], q2 = src[2], q3 = src[3];

        float gx = q0.x * INV_DX, gy = q0.y * INV_DX, gz = q0.z * INV_DX;
        int bx = (int)floorf(gx - 0.5f);
        int by = (int)floorf(gy - 0.5f);
        int bz = (int)floorf(gz - 0.5f);
        int lx0 = bx - ox, ly0 = by - oy, lz0 = bz - oz;  // in [-4..7]
        if (lx0 < -2 || ly0 < -2 || lz0 < -2) continue;   // no overlap with our cells

        float fxp = gx - (float)bx, fyp = gy - (float)by, fzp = gz - (float)bz;
        float wx[3], wy[3], wz[3];
        wx[0] = 0.5f * (1.5f - fxp) * (1.5f - fxp);
        wx[1] = 0.75f - (fxp - 1.0f) * (fxp - 1.0f);
        wx[2] = 0.5f * (fxp - 0.5f) * (fxp - 0.5f);
        wy[0] = 0.5f * (1.5f - fyp) * (1.5f - fyp);
        wy[1] = 0.75f - (fyp - 1.0f) * (fyp - 1.0f);
        wy[2] = 0.5f * (fyp - 0.5f) * (fyp - 0.5f);
        wz[0] = 0.5f * (1.5f - fzp) * (1.5f - fzp);
        wz[1] = 0.75f - (fzp - 1.0f) * (fzp - 1.0f);
        wz[2] = 0.5f * (fzp - 0.5f) * (fzp - 0.5f);

        float mvx = q0.w, mvy = q1.x, mvz = q1.y;
        float a0 = q1.z, a1 = q1.w, a2 = q2.x, a3 = q2.y, a4 = q2.z;
        float a5 = q2.w, a6 = q3.x, a7 = q3.y, a8 = q3.z;

        int axl = max(0, -lx0), axh = min(2, 7 - lx0);
        int ayl = max(0, -ly0), ayh = min(2, 7 - ly0);
        int azl = max(0, -lz0), azh = min(2, 7 - lz0);

        for (int a = axl; a <= axh; ++a) {
          float dpx = ((float)a - fxp) * DX;
          float wxa = wx[a];
          int lx = lx0 + a;
          for (int bb = ayl; bb <= ayh; ++bb) {
            float dpy = ((float)bb - fyp) * DX;
            float wxy = wxa * wy[bb];
            int ly = ly0 + bb;
            for (int c = azl; c <= azh; ++c) {
              float dpz = ((float)c - fzp) * DX;
              float w = wxy * wz[c];
              int li = (lx << 6) | (ly << 3) | (lz0 + c);
              atomAddF(&tile[0][li], w * (mvx + a0 * dpx + a1 * dpy + a2 * dpz));
              atomAddF(&tile[1][li], w * (mvy + a3 * dpx + a4 * dpy + a5 * dpz));
              atomAddF(&tile[2][li], w * (mvz + a6 * dpx + a7 * dpy + a8 * dpz));
              atomAddF(&tile[3][li], w * P_MASS);
            }
          }
        }
      }
    }
  }
  __syncthreads();

  // fused grid_op epilogue: normalize, gravity, boundary; plain coalesced stores
  float4* g4 = (float4*)grid;
  for (int i = threadIdx.x; i < 512; i += 256) {
    int lx = i >> 6, ly = (i >> 3) & 7, lz = i & 7;
    int nx = ox + lx, ny = oy + ly, nz = oz + lz;
    float m = tile[3][i];
    float vx = 0.0f, vy = 0.0f, vz = 0.0f;
    if (m > 0.0f) {
      float inv = 1.0f / fmaxf(m, 1e-10f);
      vx = tile[0][i] * inv;
      vy = tile[1][i] * inv;
      vz = tile[2][i] * inv;
      vy -= DT * GRAVITY;
    }
    if (nx < BOUND && vx < 0.0f) vx = 0.0f;
    if (nx >= N_GRID - BOUND && vx > 0.0f) vx = 0.0f;
    if (ny < BOUND && vy < 0.0f) vy = 0.0f;
    if (ny >= N_GRID - BOUND && vy > 0.0f) vy = 0.0f;
    if (nz < BOUND && vz < 0.0f) vz = 0.0f;
    if (nz >= N_GRID - BOUND && vz > 0.0f) vz = 0.0f;
    g4[(nx * N_GRID + ny) * N_GRID + nz] = make_float4(vx, vy, vz, m);
  }
}

// ---------------- G2P: gather grid velocity back to particles ----------------
__global__ __launch_bounds__(256) void mpm_g2p(
    const float* __restrict__ x, const float* __restrict__ F,
    const float* __restrict__ grid,
    float* __restrict__ out_x, float* __restrict__ out_v,
    float* __restrict__ out_C, float* __restrict__ out_F) {
  int n = blockIdx.x * blockDim.x + threadIdx.x;
  if (n >= N_PART) return;

  float px = x[n * 3 + 0], py = x[n * 3 + 1], pz = x[n * 3 + 2];
  float gx = px * INV_DX, gy = py * INV_DX, gz = pz * INV_DX;
  int bx = (int)floorf(gx - 0.5f);
  int by = (int)floorf(gy - 0.5f);
  int bz = (int)floorf(gz - 0.5f);
  float fx = gx - (float)bx, fy = gy - (float)by, fz = gz - (float)bz;

  float wx[3], wy[3], wz[3];
  wx[0] = 0.5f * (1.5f - fx) * (1.5f - fx);
  wx[1] = 0.75f - (fx - 1.0f) * (fx - 1.0f);
  wx[2] = 0.5f * (fx - 0.5f) * (fx - 0.5f);
  wy[0] = 0.5f * (1.5f - fy) * (1.5f - fy);
  wy[1] = 0.75f - (fy - 1.0f) * (fy - 1.0f);
  wy[2] = 0.5f * (fy - 0.5f) * (fy - 0.5f);
  wz[0] = 0.5f * (1.5f - fz) * (1.5f - fz);
  wz[1] = 0.75f - (fz - 1.0f) * (fz - 1.0f);
  wz[2] = 0.5f * (fz - 0.5f) * (fz - 0.5f);

  float vnx = 0.0f, vny = 0.0f, vnz = 0.0f;
  float Cn[9];
#pragma unroll
  for (int i = 0; i < 9; ++i) Cn[i] = 0.0f;

  const float4* g4 = (const float4*)grid;
#pragma unroll
  for (int a = 0; a < 3; ++a) {
#pragma unroll
    for (int bb = 0; bb < 3; ++bb) {
#pragma unroll
      for (int c = 0; c < 3; ++c) {
        float weight = wx[a] * wy[bb] * wz[c];
        float dpx = ((float)a - fx) * DX;
        float dpy = ((float)bb - fy) * DX;
        float dpz = ((float)c - fz) * DX;
        int nx = min(max(bx + a, 0), N_GRID - 1);
        int ny = min(max(by + bb, 0), N_GRID - 1);
        int nz = min(max(bz + c, 0), N_GRID - 1);
        int flat = (nx * N_GRID + ny) * N_GRID + nz;
        float4 g = g4[flat];
        vnx += weight * g.x;
        vny += weight * g.y;
        vnz += weight * g.z;
        Cn[0] += weight * g.x * dpx;
        Cn[1] += weight * g.x * dpy;
        Cn[2] += weight * g.x * dpz;
        Cn[3] += weight * g.y * dpx;
        Cn[4] += weight * g.y * dpy;
        Cn[5] += weight * g.y * dpz;
        Cn[6] += weight * g.z * dpx;
        Cn[7] += weight * g.z * dpy;
        Cn[8] += weight * g.z * dpz;
      }
    }
  }

#pragma unroll
  for (int i = 0; i < 9; ++i) Cn[i] *= C_SCALE;

  out_x[n * 3 + 0] = px + DT * vnx;
  out_x[n * 3 + 1] = py + DT * vny;
  out_x[n * 3 + 2] = pz + DT * vnz;
  out_v[n * 3 + 0] = vnx;
  out_v[n * 3 + 1] = vny;
  out_v[n * 3 + 2] = vnz;

  float A[9];
#pragma unroll
  for (int i = 0; i < 9; ++i) A[i] = DT * Cn[i];
  A[0] += 1.0f; A[4] += 1.0f; A[8] += 1.0f;

  float Fl[9];
#pragma unroll
  for (int i = 0; i < 9; ++i) Fl[i] = F[n * 9 + i];

#pragma unroll
  for (int i = 0; i < 3; ++i) {
#pragma unroll
    for (int k = 0; k < 3; ++k) {
      float s = A[i * 3 + 0] * Fl[0 * 3 + k] +
                A[i * 3 + 1] * Fl[1 * 3 + k] +
                A[i * 3 + 2] * Fl[2 * 3 + k];
      out_F[n * 9 + i * 3 + k] = s;
    }
  }

#pragma unroll
  for (int i = 0; i < 9; ++i) out_C[n * 9 + i] = Cn[i];
}

extern "C" void kernel_launch(void* const* d_in, const int* in_sizes, int n_in,
                              void* d_out, int out_size, void* d_ws, size_t ws_size,
                              hipStream_t stream) {
  const float* x      = (const float*)d_in[0];
  const float* v      = (const float*)d_in[1];
  const float* C      = (const float*)d_in[2];
  const float* F      = (const float*)d_in[3];
  const float* stress = (const float*)d_in[4];

  float* out = (float*)d_out;
  char*  ws  = (char*)d_ws;

  const size_t GRID_BYTES = (size_t)N_GRID3 * 4 * sizeof(float);   // 33.5 MB
  const size_t PAY_BYTES  = (size_t)N_PART * 4 * sizeof(float4);   // 32 MB

  float*  grid      = (float*)ws;
  float4* pay       = (float4*)(ws + GRID_BYTES);
  int*    cnt       = (int*)(ws + GRID_BYTES + PAY_BYTES);
  int*    cellStart = cnt + NFB3;        // NFB3 + 1 entries
  int*    cursor    = cellStart + NFB3 + 1;
  int*    bidArr    = cursor + NFB3;

  hipMemsetAsync(cnt, 0, NFB3 * sizeof(int), stream);

  int pblocks = (N_PART + 255) / 256;
  k_count<<<pblocks, 256, 0, stream>>>(x, bidArr, cnt);
  k_scan<<<1, 256, 0, stream>>>(cnt, cellStart, cursor);
  k_reorder<<<pblocks, 256, 0, stream>>>(x, v, C, stress, bidArr, cursor, pay);

  mpm_p2g<<<NOB3, 256, 0, stream>>>(cellStart, pay, grid);

  float* out_x = out;
  float* out_v = out + (size_t)N_PART * 3;
  float* out_C = out + (size_t)N_PART * 6;
  float* out_F = out + (size_t)N_PART * 6 + (size_t)N_PART * 9;
  mpm_g2p<<<pblocks, 256, 0, stream>>>(x, F, grid, out_x, out_v, out_C, out_F);
}

// Round 5
// 338.116 us; speedup vs baseline: 2.4061x; 2.4061x over previous
//
#include <hip/hip_runtime.h>

#define N_GRID 128
#define N_GRID3 (N_GRID * N_GRID * N_GRID)   // 2097152 cells/nodes

constexpr int   N_PART   = 500000;
constexpr float DT       = 0.0002f;
constexpr float DX       = 1.0f / 128.0f;
constexpr float INV_DX   = 128.0f;
constexpr float P_MASS   = 5.9604644775390625e-05f;   // (DX*0.5)^3 * 1000
constexpr float AFF_COEF = -7.8125e-07f;              // -DT * P_VOL * 4 * INV_DX^2
constexpr float GRAVITY  = 9.8f;
constexpr int   BOUND    = 3;
constexpr float C_SCALE  = 65536.0f;                  // 4 * INV_DX^2

// ---------------- pass 1: per-particle cell id + 2M-bin histogram ----------------
__global__ __launch_bounds__(256) void k_count(const float* __restrict__ x,
                                               int* __restrict__ cid,
                                               int* __restrict__ cnt) {
  int n = blockIdx.x * 256 + threadIdx.x;
  if (n >= N_PART) return;
  int bx = (int)floorf(x[n * 3 + 0] * INV_DX - 0.5f);
  int by = (int)floorf(x[n * 3 + 1] * INV_DX - 0.5f);
  int bz = (int)floorf(x[n * 3 + 2] * INV_DX - 0.5f);
  bx = min(max(bx, 0), N_GRID - 1);
  by = min(max(by, 0), N_GRID - 1);
  bz = min(max(bz, 0), N_GRID - 1);
  int c = (bx << 14) | (by << 7) | bz;
  cid[n] = c;
  atomicAdd(&cnt[c], 1);  // int atomic, ~1 particle/bin -> negligible contention
}

// ---------------- pass 2a: block sums (2048 blocks x 1024 bins) ----------------
__global__ __launch_bounds__(256) void k_scan1(const int* __restrict__ cnt,
                                               int* __restrict__ blkSum) {
  __shared__ int ws[4];
  int tid = threadIdx.x, lane = tid & 63, wid = tid >> 6;
  int4 v = ((const int4*)cnt)[blockIdx.x * 256 + tid];
  int s = v.x + v.y + v.z + v.w;
  for (int d = 32; d > 0; d >>= 1) s += __shfl_down(s, d);
  if (lane == 0) ws[wid] = s;
  __syncthreads();
  if (tid == 0) blkSum[blockIdx.x] = ws[0] + ws[1] + ws[2] + ws[3];
}

// ---------------- pass 2b: scan 2048 block sums (1 workgroup) ----------------
__global__ __launch_bounds__(256) void k_scan2(const int* __restrict__ blkSum,
                                               int* __restrict__ blkOff,
                                               int* __restrict__ start) {
  __shared__ int wsum[4];
  int tid = threadIdx.x, lane = tid & 63, wid = tid >> 6;
  int base = tid * 8;
  int s[8], tot = 0;
#pragma unroll
  for (int j = 0; j < 8; ++j) { s[j] = blkSum[base + j]; tot += s[j]; }
  int incl = tot;
  for (int d = 1; d < 64; d <<= 1) {
    int t = __shfl_up(incl, d);
    if (lane >= d) incl += t;
  }
  if (lane == 63) wsum[wid] = incl;
  __syncthreads();
  int woff = 0;
  for (int w = 0; w < wid; ++w) woff += wsum[w];
  int run = woff + incl - tot;
#pragma unroll
  for (int j = 0; j < 8; ++j) { blkOff[base + j] = run; run += s[j]; }
  if (tid == 255) start[N_GRID3] = run;  // == N_PART
}

// ------- pass 2c: in-block exclusive scan + offset; cursor written in-place over cnt -------
__global__ __launch_bounds__(256) void k_scan3(int* __restrict__ cnt,
                                               const int* __restrict__ blkOff,
                                               int* __restrict__ start) {
  __shared__ int wsum[4];
  int tid = threadIdx.x, lane = tid & 63, wid = tid >> 6;
  int b = blockIdx.x;
  int4 v = ((const int4*)cnt)[b * 256 + tid];
  int s = v.x + v.y + v.z + v.w;
  int incl = s;
  for (int d = 1; d < 64; d <<= 1) {
    int t = __shfl_up(incl, d);
    if (lane >= d) incl += t;
  }
  if (lane == 63) wsum[wid] = incl;
  __syncthreads();
  int woff = blkOff[b];
  for (int w = 0; w < wid; ++w) woff += wsum[w];
  int run = woff + incl - s;
  int i0 = (b * 256 + tid) * 4;
  int r0 = run, r1 = r0 + v.x, r2 = r1 + v.y, r3 = r2 + v.z;
  start[i0 + 0] = r0; start[i0 + 1] = r1; start[i0 + 2] = r2; start[i0 + 3] = r3;
  cnt[i0 + 0] = r0; cnt[i0 + 1] = r1; cnt[i0 + 2] = r2; cnt[i0 + 3] = r3;  // cursor
}

// ---------------- pass 3: reorder + precompute 64B particle payload ----------------
// payload[pos] = { (px,py,pz,mvx), (mvy,mvz,a0,a1), (a2,a3,a4,a5), (a6,a7,a8,pad) }
__global__ __launch_bounds__(256) void k_reorder(
    const float* __restrict__ x, const float* __restrict__ v,
    const float* __restrict__ C, const float* __restrict__ S,
    const int* __restrict__ cid, int* __restrict__ cursor,
    float4* __restrict__ pay) {
  int n = blockIdx.x * 256 + threadIdx.x;
  if (n >= N_PART) return;
  int pos = atomicAdd(&cursor[cid[n]], 1);

  float px = x[n * 3 + 0], py = x[n * 3 + 1], pz = x[n * 3 + 2];
  float mvx = P_MASS * v[n * 3 + 0];
  float mvy = P_MASS * v[n * 3 + 1];
  float mvz = P_MASS * v[n * 3 + 2];
  float aff[9];
#pragma unroll
  for (int k = 0; k < 9; ++k)
    aff[k] = AFF_COEF * S[n * 9 + k] + P_MASS * C[n * 9 + k];

  float4* dst = pay + (size_t)pos * 4;
  dst[0] = make_float4(px, py, pz, mvx);
  dst[1] = make_float4(mvy, mvz, aff[0], aff[1]);
  dst[2] = make_float4(aff[2], aff[3], aff[4], aff[5]);
  dst[3] = make_float4(aff[6], aff[7], aff[8], 0.0f);
}

// quadratic B-spline weight for static offset o (folds after unroll)
__device__ __forceinline__ float wq(int o, float f) {
  if (o == 0) return 0.5f * (1.5f - f) * (1.5f - f);
  if (o == 1) return 0.75f - (f - 1.0f) * (f - 1.0f);
  return 0.5f * (f - 0.5f) * (f - 0.5f);
}

// ---------------- P2G gather: one thread per node, register accumulation ----------------
// Zero atomics, zero LDS. Node n gathers particles with base cell in [n-2,n]^3
// (z is contiguous in the sorted order). Fused normalize/gravity/boundary epilogue.
__global__ __launch_bounds__(256) void mpm_p2g(
    const int* __restrict__ start, const float4* __restrict__ pay,
    float* __restrict__ grid /* [N_GRID3][4] final velocities */) {
  int n = blockIdx.x * 256 + threadIdx.x;
  if (n >= N_GRID3) return;
  int nz = n & 127, ny = (n >> 7) & 127, nx = n >> 14;

  float vx = 0.0f, vy = 0.0f, vz = 0.0f, m = 0.0f;
  int got = 0;
  int zlo = max(nz - 2, 0);

#pragma unroll
  for (int dy = -2; dy <= 0; ++dy) {
    int cy = ny + dy;
    if (cy < 0) continue;
#pragma unroll
    for (int dx = -2; dx <= 0; ++dx) {
      int cx = nx + dx;
      if (cx < 0) continue;
      const int ox = -dx, oy = -dy;  // static after unroll
      int rowb = (cx << 14) | (cy << 7);
      int s = start[rowb + zlo];
      int e = start[rowb + nz + 1];
      got |= (e - s);
      for (int i = s; i < e; ++i) {
        const float4* src = pay + (size_t)i * 4;
        float4 q0 = src[0], q1 = src[1], q2 = src[2], q3 = src[3];

        float fx = q0.x * INV_DX - (float)cx;   // base_x == cx by construction
        float fy = q0.y * INV_DX - (float)cy;
        float gz = q0.z * INV_DX;
        float bzf = floorf(gz - 0.5f);
        float fz = gz - bzf;
        int oz = nz - (int)bzf;
        if (oz < 0 || oz > 2) continue;  // only possible for domain-clamped bins

        float wxy = wq(ox, fx) * wq(oy, fy);
        float wz0 = 0.5f * (1.5f - fz) * (1.5f - fz);
        float wz1 = 0.75f - (fz - 1.0f) * (fz - 1.0f);
        float wz2 = 0.5f * (fz - 0.5f) * (fz - 0.5f);
        float wzz = (oz == 0) ? wz0 : ((oz == 1) ? wz1 : wz2);
        float w = wxy * wzz;

        float dpx = ((float)ox - fx) * DX;
        float dpy = ((float)oy - fy) * DX;
        float dpz = ((float)oz - fz) * DX;

        vx += w * (q0.w + q1.z * dpx + q1.w * dpy + q2.x * dpz);
        vy += w * (q1.x + q2.y * dpx + q2.z * dpy + q2.w * dpz);
        vz += w * (q1.y + q3.x * dpx + q3.y * dpy + q3.z * dpz);
        m  += w * P_MASS;
      }
    }
  }

  if (!got) return;  // node never read by G2P (no particle stencil touches it)

  float ovx = 0.0f, ovy = 0.0f, ovz = 0.0f;
  if (m > 0.0f) {
    float inv = 1.0f / fmaxf(m, 1e-10f);
    ovx = vx * inv;
    ovy = vy * inv;
    ovz = vz * inv;
    ovy -= DT * GRAVITY;
  }
  if (nx < BOUND && ovx < 0.0f) ovx = 0.0f;
  if (nx >= N_GRID - BOUND && ovx > 0.0f) ovx = 0.0f;
  if (ny < BOUND && ovy < 0.0f) ovy = 0.0f;
  if (ny >= N_GRID - BOUND && ovy > 0.0f) ovy = 0.0f;
  if (nz < BOUND && ovz < 0.0f) ovz = 0.0f;
  if (nz >= N_GRID - BOUND && ovz > 0.0f) ovz = 0.0f;
  ((float4*)grid)[n] = make_float4(ovx, ovy, ovz, m);
}

// ---------------- G2P: gather grid velocity back to particles ----------------
__global__ __launch_bounds__(256) void mpm_g2p(
    const float* __restrict__ x, const float* __restrict__ F,
    const float* __restrict__ grid,
    float* __restrict__ out_x, float* __restrict__ out_v,
    float* __restrict__ out_C, float* __restrict__ out_F) {
  int n = blockIdx.x * blockDim.x + threadIdx.x;
  if (n >= N_PART) return;

  float px = x[n * 3 + 0], py = x[n * 3 + 1], pz = x[n * 3 + 2];
  float gx = px * INV_DX, gy = py * INV_DX, gz = pz * INV_DX;
  int bx = (int)floorf(gx - 0.5f);
  int by = (int)floorf(gy - 0.5f);
  int bz = (int)floorf(gz - 0.5f);
  float fx = gx - (float)bx, fy = gy - (float)by, fz = gz - (float)bz;

  float wx[3], wy[3], wz[3];
  wx[0] = 0.5f * (1.5f - fx) * (1.5f - fx);
  wx[1] = 0.75f - (fx - 1.0f) * (fx - 1.0f);
  wx[2] = 0.5f * (fx - 0.5f) * (fx - 0.5f);
  wy[0] = 0.5f * (1.5f - fy) * (1.5f - fy);
  wy[1] = 0.75f - (fy - 1.0f) * (fy - 1.0f);
  wy[2] = 0.5f * (fy - 0.5f) * (fy - 0.5f);
  wz[0] = 0.5f * (1.5f - fz) * (1.5f - fz);
  wz[1] = 0.75f - (fz - 1.0f) * (fz - 1.0f);
  wz[2] = 0.5f * (fz - 0.5f) * (fz - 0.5f);

  float vnx = 0.0f, vny = 0.0f, vnz = 0.0f;
  float Cn[9];
#pragma unroll
  for (int i = 0; i < 9; ++i) Cn[i] = 0.0f;

  const float4* g4 = (const float4*)grid;
#pragma unroll
  for (int a = 0; a < 3; ++a) {
#pragma unroll
    for (int bb = 0; bb < 3; ++bb) {
#pragma unroll
      for (int c = 0; c < 3; ++c) {
        float weight = wx[a] * wy[bb] * wz[c];
        float dpx = ((float)a - fx) * DX;
        float dpy = ((float)bb - fy) * DX;
        float dpz = ((float)c - fz) * DX;
        int nxg = min(max(bx + a, 0), N_GRID - 1);
        int nyg = min(max(by + bb, 0), N_GRID - 1);
        int nzg = min(max(bz + c, 0), N_GRID - 1);
        int flat = (nxg * N_GRID + nyg) * N_GRID + nzg;
        float4 g = g4[flat];
        vnx += weight * g.x;
        vny += weight * g.y;
        vnz += weight * g.z;
        Cn[0] += weight * g.x * dpx;
        Cn[1] += weight * g.x * dpy;
        Cn[2] += weight * g.x * dpz;
        Cn[3] += weight * g.y * dpx;
        Cn[4] += weight * g.y * dpy;
        Cn[5] += weight * g.y * dpz;
        Cn[6] += weight * g.z * dpx;
        Cn[7] += weight * g.z * dpy;
        Cn[8] += weight * g.z * dpz;
      }
    }
  }

#pragma unroll
  for (int i = 0; i < 9; ++i) Cn[i] *= C_SCALE;

  out_x[n * 3 + 0] = px + DT * vnx;
  out_x[n * 3 + 1] = py + DT * vny;
  out_x[n * 3 + 2] = pz + DT * vnz;
  out_v[n * 3 + 0] = vnx;
  out_v[n * 3 + 1] = vny;
  out_v[n * 3 + 2] = vnz;

  float A[9];
#pragma unroll
  for (int i = 0; i < 9; ++i) A[i] = DT * Cn[i];
  A[0] += 1.0f; A[4] += 1.0f; A[8] += 1.0f;

  float Fl[9];
#pragma unroll
  for (int i = 0; i < 9; ++i) Fl[i] = F[n * 9 + i];

#pragma unroll
  for (int i = 0; i < 3; ++i) {
#pragma unroll
    for (int k = 0; k < 3; ++k) {
      float s = A[i * 3 + 0] * Fl[0 * 3 + k] +
                A[i * 3 + 1] * Fl[1 * 3 + k] +
                A[i * 3 + 2] * Fl[2 * 3 + k];
      out_F[n * 9 + i * 3 + k] = s;
    }
  }

#pragma unroll
  for (int i = 0; i < 9; ++i) out_C[n * 9 + i] = Cn[i];
}

extern "C" void kernel_launch(void* const* d_in, const int* in_sizes, int n_in,
                              void* d_out, int out_size, void* d_ws, size_t ws_size,
                              hipStream_t stream) {
  const float* x      = (const float*)d_in[0];
  const float* v      = (const float*)d_in[1];
  const float* C      = (const float*)d_in[2];
  const float* F      = (const float*)d_in[3];
  const float* stress = (const float*)d_in[4];

  float* out = (float*)d_out;
  char*  ws  = (char*)d_ws;

  const size_t GRID_BYTES  = (size_t)N_GRID3 * 4 * sizeof(float);   // 33.5 MB
  const size_t PAY_BYTES   = (size_t)N_PART * 4 * sizeof(float4);   // 32 MB
  const size_t CNT_BYTES   = (size_t)N_GRID3 * sizeof(int);         // 8 MB
  const size_t START_BYTES = ((size_t)N_GRID3 + 1) * sizeof(int);   // 8 MB

  float*  grid   = (float*)ws;
  float4* pay    = (float4*)(ws + GRID_BYTES);
  int*    cnt    = (int*)(ws + GRID_BYTES + PAY_BYTES);             // doubles as cursor
  int*    startp = (int*)(ws + GRID_BYTES + PAY_BYTES + CNT_BYTES);
  int*    cidArr = (int*)(ws + GRID_BYTES + PAY_BYTES + CNT_BYTES + START_BYTES);
  int*    blkSum = cidArr + N_PART;
  int*    blkOff = blkSum + 2048;

  hipMemsetAsync(cnt, 0, CNT_BYTES, stream);

  int pblocks = (N_PART + 255) / 256;
  k_count<<<pblocks, 256, 0, stream>>>(x, cidArr, cnt);
  k_scan1<<<2048, 256, 0, stream>>>(cnt, blkSum);
  k_scan2<<<1, 256, 0, stream>>>(blkSum, blkOff, startp);
  k_scan3<<<2048, 256, 0, stream>>>(cnt, blkOff, startp);
  k_reorder<<<pblocks, 256, 0, stream>>>(x, v, C, stress, cidArr, cnt, pay);

  mpm_p2g<<<N_GRID3 / 256, 256, 0, stream>>>(startp, pay, grid);

  float* out_x = out;
  float* out_v = out + (size_t)N_PART * 3;
  float* out_C = out + (size_t)N_PART * 6;
  float* out_F = out + (size_t)N_PART * 6 + (size_t)N_PART * 9;
  mpm_g2p<<<pblocks, 256, 0, stream>>>(x, F, grid, out_x, out_v, out_C, out_F);
}

// Round 6
// 264.784 us; speedup vs baseline: 3.0724x; 1.2770x over previous
//
#include <hip/hip_runtime.h>

#define N_GRID 128
#define N_GRID3 (N_GRID * N_GRID * N_GRID)   // 2097152 cells/nodes

constexpr int   N_PART   = 500000;
constexpr float DT       = 0.0002f;
constexpr float DX       = 1.0f / 128.0f;
constexpr float INV_DX   = 128.0f;
constexpr float P_MASS   = 5.9604644775390625e-05f;   // (DX*0.5)^3 * 1000
constexpr float AFF_COEF = -7.8125e-07f;              // -DT * P_VOL * 4 * INV_DX^2
constexpr float GRAVITY  = 9.8f;
constexpr int   BOUND    = 3;
constexpr float C_SCALE  = 65536.0f;                  // 4 * INV_DX^2
constexpr int   ZQ       = 4;                         // z-nodes per p2g thread

// ---------------- pass 1: per-particle cell id + 2M-bin histogram ----------------
__global__ __launch_bounds__(256) void k_count(const float* __restrict__ x,
                                               int* __restrict__ cid,
                                               int* __restrict__ cnt) {
  int n = blockIdx.x * 256 + threadIdx.x;
  if (n >= N_PART) return;
  int bx = (int)floorf(x[n * 3 + 0] * INV_DX - 0.5f);
  int by = (int)floorf(x[n * 3 + 1] * INV_DX - 0.5f);
  int bz = (int)floorf(x[n * 3 + 2] * INV_DX - 0.5f);
  bx = min(max(bx, 0), N_GRID - 1);
  by = min(max(by, 0), N_GRID - 1);
  bz = min(max(bz, 0), N_GRID - 1);
  int c = (bx << 14) | (by << 7) | bz;
  cid[n] = c;
  atomicAdd(&cnt[c], 1);
}

// ---------------- pass 2a: block sums (2048 blocks x 1024 bins) ----------------
__global__ __launch_bounds__(256) void k_scan1(const int* __restrict__ cnt,
                                               int* __restrict__ blkSum) {
  __shared__ int ws[4];
  int tid = threadIdx.x, lane = tid & 63, wid = tid >> 6;
  int4 v = ((const int4*)cnt)[blockIdx.x * 256 + tid];
  int s = v.x + v.y + v.z + v.w;
  for (int d = 32; d > 0; d >>= 1) s += __shfl_down(s, d);
  if (lane == 0) ws[wid] = s;
  __syncthreads();
  if (tid == 0) blkSum[blockIdx.x] = ws[0] + ws[1] + ws[2] + ws[3];
}

// ---------------- pass 2b: scan 2048 block sums (1 workgroup) ----------------
__global__ __launch_bounds__(256) void k_scan2(const int* __restrict__ blkSum,
                                               int* __restrict__ blkOff,
                                               int* __restrict__ start) {
  __shared__ int wsum[4];
  int tid = threadIdx.x, lane = tid & 63, wid = tid >> 6;
  int base = tid * 8;
  int s[8], tot = 0;
#pragma unroll
  for (int j = 0; j < 8; ++j) { s[j] = blkSum[base + j]; tot += s[j]; }
  int incl = tot;
  for (int d = 1; d < 64; d <<= 1) {
    int t = __shfl_up(incl, d);
    if (lane >= d) incl += t;
  }
  if (lane == 63) wsum[wid] = incl;
  __syncthreads();
  int woff = 0;
  for (int w = 0; w < wid; ++w) woff += wsum[w];
  int run = woff + incl - tot;
#pragma unroll
  for (int j = 0; j < 8; ++j) { blkOff[base + j] = run; run += s[j]; }
  if (tid == 255) start[N_GRID3] = run;  // == N_PART
}

// ------- pass 2c: in-block exclusive scan + offset; cursor written in-place over cnt -------
__global__ __launch_bounds__(256) void k_scan3(int* __restrict__ cnt,
                                               const int* __restrict__ blkOff,
                                               int* __restrict__ start) {
  __shared__ int wsum[4];
  int tid = threadIdx.x, lane = tid & 63, wid = tid >> 6;
  int b = blockIdx.x;
  int4 v = ((const int4*)cnt)[b * 256 + tid];
  int s = v.x + v.y + v.z + v.w;
  int incl = s;
  for (int d = 1; d < 64; d <<= 1) {
    int t = __shfl_up(incl, d);
    if (lane >= d) incl += t;
  }
  if (lane == 63) wsum[wid] = incl;
  __syncthreads();
  int woff = blkOff[b];
  for (int w = 0; w < wid; ++w) woff += wsum[w];
  int run = woff + incl - s;
  int i0 = (b * 256 + tid) * 4;
  int r0 = run, r1 = r0 + v.x, r2 = r1 + v.y, r3 = r2 + v.z;
  start[i0 + 0] = r0; start[i0 + 1] = r1; start[i0 + 2] = r2; start[i0 + 3] = r3;
  cnt[i0 + 0] = r0; cnt[i0 + 1] = r1; cnt[i0 + 2] = r2; cnt[i0 + 3] = r3;  // cursor
}

// ---------------- pass 3: reorder + precompute 64B particle payload ----------------
// payload[pos] = { (px,py,pz,mvx), (mvy,mvz,a0,a1), (a2,a3,a4,a5), (a6,a7,a8,pad) }
__global__ __launch_bounds__(256) void k_reorder(
    const float* __restrict__ x, const float* __restrict__ v,
    const float* __restrict__ C, const float* __restrict__ S,
    const int* __restrict__ cid, int* __restrict__ cursor,
    float4* __restrict__ pay) {
  int n = blockIdx.x * 256 + threadIdx.x;
  if (n >= N_PART) return;
  int pos = atomicAdd(&cursor[cid[n]], 1);

  float px = x[n * 3 + 0], py = x[n * 3 + 1], pz = x[n * 3 + 2];
  float mvx = P_MASS * v[n * 3 + 0];
  float mvy = P_MASS * v[n * 3 + 1];
  float mvz = P_MASS * v[n * 3 + 2];
  float aff[9];
#pragma unroll
  for (int k = 0; k < 9; ++k)
    aff[k] = AFF_COEF * S[n * 9 + k] + P_MASS * C[n * 9 + k];

  float4* dst = pay + (size_t)pos * 4;
  dst[0] = make_float4(px, py, pz, mvx);
  dst[1] = make_float4(mvy, mvz, aff[0], aff[1]);
  dst[2] = make_float4(aff[2], aff[3], aff[4], aff[5]);
  dst[3] = make_float4(aff[6], aff[7], aff[8], 0.0f);
}

// quadratic B-spline weight for static offset o (folds after unroll)
__device__ __forceinline__ float wq(int o, float f) {
  if (o == 0) return 0.5f * (1.5f - f) * (1.5f - f);
  if (o == 1) return 0.75f - (f - 1.0f) * (f - 1.0f);
  return 0.5f * (f - 0.5f) * (f - 0.5f);
}

// ---------------- P2G gather: one thread per 4 z-consecutive nodes ----------------
// Zero atomics, zero LDS. All 4 nodes share (nx,ny) -> same 9 (cx,cy) columns;
// z-range widened to 6 cells; each particle read once per column serves up to
// 3 of the 4 nodes. Fused normalize/gravity/boundary epilogue.
__global__ __launch_bounds__(256) void mpm_p2g(
    const int* __restrict__ start, const float4* __restrict__ pay,
    float* __restrict__ grid /* [N_GRID3][4] final velocities */) {
  int t = blockIdx.x * 256 + threadIdx.x;
  if (t >= N_GRID3 / ZQ) return;
  int nzq = t & 31;            // 32 quads per z-column
  int ny = (t >> 5) & 127;
  int nx = t >> 12;
  int nz0 = nzq * ZQ;
  int zb0 = nz0 - 2;           // first contributing cell (may be <0)

  float accx[ZQ], accy[ZQ], accz[ZQ], accm[ZQ];
#pragma unroll
  for (int k = 0; k < ZQ; ++k) { accx[k] = 0.f; accy[k] = 0.f; accz[k] = 0.f; accm[k] = 0.f; }
  int gotmask = 0;

#pragma unroll
  for (int dy = -2; dy <= 0; ++dy) {
    int cy = ny + dy;
    if (cy < 0) continue;
#pragma unroll
    for (int dx = -2; dx <= 0; ++dx) {
      int cx = nx + dx;
      if (cx < 0) continue;
      const int ox = -dx, oy = -dy;  // static after unroll
      int rowb = (cx << 14) | (cy << 7);

      int S[7];
#pragma unroll
      for (int j = 0; j < 7; ++j) S[j] = start[rowb + max(zb0 + j, 0)];
#pragma unroll
      for (int k = 0; k < ZQ; ++k)
        gotmask |= (S[k + 3] > S[k]) ? (1 << k) : 0;

      for (int i = S[0]; i < S[6]; ++i) {
        const float4* src = pay + (size_t)i * 4;
        float4 q0 = src[0], q1 = src[1], q2 = src[2], q3 = src[3];

        float fx = q0.x * INV_DX - (float)cx;   // base_x == cx by construction
        float fy = q0.y * INV_DX - (float)cy;
        float gz = q0.z * INV_DX;
        float bzf = floorf(gz - 0.5f);
        float fz = gz - bzf;
        int oz0 = nz0 - (int)bzf;

        float wxy = wq(ox, fx) * wq(oy, fy);
        float dpx = ((float)ox - fx) * DX;
        float dpy = ((float)oy - fy) * DX;
        float wz0 = 0.5f * (1.5f - fz) * (1.5f - fz);
        float wz1 = 0.75f - (fz - 1.0f) * (fz - 1.0f);
        float wz2 = 0.5f * (fz - 0.5f) * (fz - 0.5f);

        // dpz-independent partial sums (shared across the quad's nodes)
        float sx = q0.w + q1.z * dpx + q1.w * dpy;   // a2 = q2.x pairs with dpz
        float sy = q1.x + q2.y * dpx + q2.z * dpy;   // a5 = q2.w
        float sz = q1.y + q3.x * dpx + q3.y * dpy;   // a8 = q3.z
        float wm = wxy * P_MASS;

#pragma unroll
        for (int k = 0; k < ZQ; ++k) {
          int oz = oz0 + k;
          if (oz < 0 || oz > 2) continue;
          float wzz = (oz == 0) ? wz0 : ((oz == 1) ? wz1 : wz2);
          float w = wxy * wzz;
          float dpz = ((float)oz - fz) * DX;
          accx[k] += w * (sx + q2.x * dpz);
          accy[k] += w * (sy + q2.w * dpz);
          accz[k] += w * (sz + q3.z * dpz);
          accm[k] += wzz * wm;
        }
      }
    }
  }

  if (!gotmask) return;

  float4* g4 = (float4*)grid;
#pragma unroll
  for (int k = 0; k < ZQ; ++k) {
    if (!((gotmask >> k) & 1)) continue;  // node never read by G2P
    int nz = nz0 + k;
    float m = accm[k];
    float ovx = 0.0f, ovy = 0.0f, ovz = 0.0f;
    if (m > 0.0f) {
      float inv = 1.0f / fmaxf(m, 1e-10f);
      ovx = accx[k] * inv;
      ovy = accy[k] * inv;
      ovz = accz[k] * inv;
      ovy -= DT * GRAVITY;
    }
    if (nx < BOUND && ovx < 0.0f) ovx = 0.0f;
    if (nx >= N_GRID - BOUND && ovx > 0.0f) ovx = 0.0f;
    if (ny < BOUND && ovy < 0.0f) ovy = 0.0f;
    if (ny >= N_GRID - BOUND && ovy > 0.0f) ovy = 0.0f;
    if (nz < BOUND && ovz < 0.0f) ovz = 0.0f;
    if (nz >= N_GRID - BOUND && ovz > 0.0f) ovz = 0.0f;
    g4[(nx << 14) | (ny << 7) | nz] = make_float4(ovx, ovy, ovz, m);
  }
}

// ---------------- G2P: gather grid velocity back to particles ----------------
__global__ __launch_bounds__(256) void mpm_g2p(
    const float* __restrict__ x, const float* __restrict__ F,
    const float* __restrict__ grid,
    float* __restrict__ out_x, float* __restrict__ out_v,
    float* __restrict__ out_C, float* __restrict__ out_F) {
  int n = blockIdx.x * blockDim.x + threadIdx.x;
  if (n >= N_PART) return;

  float px = x[n * 3 + 0], py = x[n * 3 + 1], pz = x[n * 3 + 2];
  float gx = px * INV_DX, gy = py * INV_DX, gz = pz * INV_DX;
  int bx = (int)floorf(gx - 0.5f);
  int by = (int)floorf(gy - 0.5f);
  int bz = (int)floorf(gz - 0.5f);
  float fx = gx - (float)bx, fy = gy - (float)by, fz = gz - (float)bz;

  float wx[3], wy[3], wz[3];
  wx[0] = 0.5f * (1.5f - fx) * (1.5f - fx);
  wx[1] = 0.75f - (fx - 1.0f) * (fx - 1.0f);
  wx[2] = 0.5f * (fx - 0.5f) * (fx - 0.5f);
  wy[0] = 0.5f * (1.5f - fy) * (1.5f - fy);
  wy[1] = 0.75f - (fy - 1.0f) * (fy - 1.0f);
  wy[2] = 0.5f * (fy - 0.5f) * (fy - 0.5f);
  wz[0] = 0.5f * (1.5f - fz) * (1.5f - fz);
  wz[1] = 0.75f - (fz - 1.0f) * (fz - 1.0f);
  wz[2] = 0.5f * (fz - 0.5f) * (fz - 0.5f);

  float vnx = 0.0f, vny = 0.0f, vnz = 0.0f;
  float Cn[9];
#pragma unroll
  for (int i = 0; i < 9; ++i) Cn[i] = 0.0f;

  const float4* g4 = (const float4*)grid;
#pragma unroll
  for (int a = 0; a < 3; ++a) {
#pragma unroll
    for (int bb = 0; bb < 3; ++bb) {
#pragma unroll
      for (int c = 0; c < 3; ++c) {
        float weight = wx[a] * wy[bb] * wz[c];
        float dpx = ((float)a - fx) * DX;
        float dpy = ((float)bb - fy) * DX;
        float dpz = ((float)c - fz) * DX;
        int nxg = min(max(bx + a, 0), N_GRID - 1);
        int nyg = min(max(by + bb, 0), N_GRID - 1);
        int nzg = min(max(bz + c, 0), N_GRID - 1);
        int flat = (nxg * N_GRID + nyg) * N_GRID + nzg;
        float4 g = g4[flat];
        vnx += weight * g.x;
        vny += weight * g.y;
        vnz += weight * g.z;
        Cn[0] += weight * g.x * dpx;
        Cn[1] += weight * g.x * dpy;
        Cn[2] += weight * g.x * dpz;
        Cn[3] += weight * g.y * dpx;
        Cn[4] += weight * g.y * dpy;
        Cn[5] += weight * g.y * dpz;
        Cn[6] += weight * g.z * dpx;
        Cn[7] += weight * g.z * dpy;
        Cn[8] += weight * g.z * dpz;
      }
    }
  }

#pragma unroll
  for (int i = 0; i < 9; ++i) Cn[i] *= C_SCALE;

  out_x[n * 3 + 0] = px + DT * vnx;
  out_x[n * 3 + 1] = py + DT * vny;
  out_x[n * 3 + 2] = pz + DT * vnz;
  out_v[n * 3 + 0] = vnx;
  out_v[n * 3 + 1] = vny;
  out_v[n * 3 + 2] = vnz;

  float A[9];
#pragma unroll
  for (int i = 0; i < 9; ++i) A[i] = DT * Cn[i];
  A[0] += 1.0f; A[4] += 1.0f; A[8] += 1.0f;

  float Fl[9];
#pragma unroll
  for (int i = 0; i < 9; ++i) Fl[i] = F[n * 9 + i];

#pragma unroll
  for (int i = 0; i < 3; ++i) {
#pragma unroll
    for (int k = 0; k < 3; ++k) {
      float s = A[i * 3 + 0] * Fl[0 * 3 + k] +
                A[i * 3 + 1] * Fl[1 * 3 + k] +
                A[i * 3 + 2] * Fl[2 * 3 + k];
      out_F[n * 9 + i * 3 + k] = s;
    }
  }

#pragma unroll
  for (int i = 0; i < 9; ++i) out_C[n * 9 + i] = Cn[i];
}

extern "C" void kernel_launch(void* const* d_in, const int* in_sizes, int n_in,
                              void* d_out, int out_size, void* d_ws, size_t ws_size,
                              hipStream_t stream) {
  const float* x      = (const float*)d_in[0];
  const float* v      = (const float*)d_in[1];
  const float* C      = (const float*)d_in[2];
  const float* F      = (const float*)d_in[3];
  const float* stress = (const float*)d_in[4];

  float* out = (float*)d_out;
  char*  ws  = (char*)d_ws;

  const size_t GRID_BYTES  = (size_t)N_GRID3 * 4 * sizeof(float);   // 33.5 MB
  const size_t PAY_BYTES   = (size_t)N_PART * 4 * sizeof(float4);   // 32 MB
  const size_t CNT_BYTES   = (size_t)N_GRID3 * sizeof(int);         // 8 MB
  const size_t START_BYTES = ((size_t)N_GRID3 + 1) * sizeof(int);   // 8 MB

  float*  grid   = (float*)ws;
  float4* pay    = (float4*)(ws + GRID_BYTES);
  int*    cnt    = (int*)(ws + GRID_BYTES + PAY_BYTES);             // doubles as cursor
  int*    startp = (int*)(ws + GRID_BYTES + PAY_BYTES + CNT_BYTES);
  int*    cidArr = (int*)(ws + GRID_BYTES + PAY_BYTES + CNT_BYTES + START_BYTES);
  int*    blkSum = cidArr + N_PART;
  int*    blkOff = blkSum + 2048;

  hipMemsetAsync(cnt, 0, CNT_BYTES, stream);

  int pblocks = (N_PART + 255) / 256;
  k_count<<<pblocks, 256, 0, stream>>>(x, cidArr, cnt);
  k_scan1<<<2048, 256, 0, stream>>>(cnt, blkSum);
  k_scan2<<<1, 256, 0, stream>>>(blkSum, blkOff, startp);
  k_scan3<<<2048, 256, 0, stream>>>(cnt, blkOff, startp);
  k_reorder<<<pblocks, 256, 0, stream>>>(x, v, C, stress, cidArr, cnt, pay);

  mpm_p2g<<<(N_GRID3 / ZQ) / 256, 256, 0, stream>>>(startp, pay, grid);

  float* out_x = out;
  float* out_v = out + (size_t)N_PART * 3;
  float* out_C = out + (size_t)N_PART * 6;
  float* out_F = out + (size_t)N_PART * 6 + (size_t)N_PART * 9;
  mpm_g2p<<<pblocks, 256, 0, stream>>>(x, F, grid, out_x, out_v, out_C, out_F);
}